// Round 1
// baseline (331.692 us; speedup 1.0000x reference)
//
#include <hip/hip_runtime.h>

#define N_EDGES 160000
#define C_EMB 32
#define N_RBF 32
#define EPB 16
#define THREADS 256

__global__ __launch_bounds__(THREADS) void edge_embed_kernel(
    const int* __restrict__ atomic_numbers,   // (N_ATOMS,)
    const int* __restrict__ nbr,              // (2, N_EDGES) flat
    const float* __restrict__ ev,             // (N_EDGES, 3)
    const float* __restrict__ z_table,        // (119, 32)
    const float* __restrict__ z_map_W,        // (32, 64)
    const float* __restrict__ dense_W,        // (96, 32)
    const float* __restrict__ dense_b,        // (96,)
    const float* __restrict__ rbf_beta,       // (32,)
    const float* __restrict__ rbf_centres,    // (32,)
    float* __restrict__ out)                  // 3 * N_EDGES * 288 floats
{
    __shared__ float s_hi[EPB][C_EMB];
    __shared__ float s_hj[EPB][C_EMB];
    __shared__ float s_rbf[EPB][N_RBF];
    __shared__ float s_hz[EPB][C_EMB];
    __shared__ float s_c[EPB][96];
    __shared__ float s_basis[EPB][28];   // [0..8]=I, [9..17]=A0, [18..26]=S0
    __shared__ float s_env[EPB];

    const int tid = threadIdx.x;
    const int e0 = blockIdx.x * EPB;

    // P0a: gather per-edge atom embeddings into LDS
    for (int idx = tid; idx < EPB * C_EMB; idx += THREADS) {
        int e = idx >> 5, k = idx & 31;
        int ge = e0 + e;
        int zi = atomic_numbers[nbr[ge]];
        int zj = atomic_numbers[nbr[N_EDGES + ge]];
        s_hi[e][k] = z_table[zi * C_EMB + k];
        s_hj[e][k] = z_table[zj * C_EMB + k];
    }

    // P0b: RBF + envelope
    for (int idx = tid; idx < EPB * N_RBF; idx += THREADS) {
        int e = idx >> 5, n = idx & 31;
        int ge = e0 + e;
        float x = ev[ge * 3 + 0], y = ev[ge * 3 + 1], z = ev[ge * 3 + 2];
        float r = sqrtf(x * x + y * y + z * z);
        float er = __expf(-r);
        float d = er - rbf_centres[n];
        s_rbf[e][n] = __expf(-rbf_beta[n] * d * d);
        if (n == 0) {
            s_env[e] = (r < 5.0f)
                ? 0.5f * (__cosf(3.14159265358979323f * r * 0.2f) + 1.0f)
                : 0.0f;
        }
    }

    // P0c: geometric basis (I, A0, S0) per edge
    for (int idx = tid; idx < EPB * 27; idx += THREADS) {
        int e = idx / 27, t = idx - e * 27;
        int ge = e0 + e;
        float x = ev[ge * 3 + 0], y = ev[ge * 3 + 1], z = ev[ge * 3 + 2];
        float rinv = rsqrtf(x * x + y * y + z * z);
        float vx = x * rinv, vy = y * rinv, vz = z * rinv;
        float val;
        if (t < 9) {
            val = (t == 0 || t == 4 || t == 8) ? 1.0f : 0.0f;
        } else if (t < 18) {
            int p = t - 9;
            // A0 = [0,-vz,vy, vz,0,-vx, -vy,vx,0]
            switch (p) {
                case 1: val = -vz; break;
                case 2: val =  vy; break;
                case 3: val =  vz; break;
                case 5: val = -vx; break;
                case 6: val = -vy; break;
                case 7: val =  vx; break;
                default: val = 0.0f; break;
            }
        } else {
            int p = t - 18;
            int i = p / 3, j = p - 3 * i;
            float ri = (i == 0) ? vx : ((i == 1) ? vy : vz);
            float rj = (j == 0) ? vx : ((j == 1) ? vy : vz);
            val = ri * rj - ((i == j) ? (1.0f / 3.0f) : 0.0f);
        }
        s_basis[e][t] = val;
    }
    __syncthreads();

    // P1: h_z[e][c] = sum_k h_i[k]*W[c,k] + h_j[k]*W[c,32+k]
    for (int idx = tid; idx < EPB * C_EMB; idx += THREADS) {
        int e = idx >> 5, cc = idx & 31;
        const float4* Wi  = (const float4*)(z_map_W + cc * 64);
        const float4* hi4 = (const float4*)s_hi[e];
        const float4* hj4 = (const float4*)s_hj[e];
        float acc = 0.0f;
        #pragma unroll
        for (int k = 0; k < 8; ++k) {
            float4 w = Wi[k]; float4 h = hi4[k];
            acc += w.x * h.x + w.y * h.y + w.z * h.z + w.w * h.w;
        }
        #pragma unroll
        for (int k = 0; k < 8; ++k) {
            float4 w = Wi[8 + k]; float4 h = hj4[k];
            acc += w.x * h.x + w.y * h.y + w.z * h.z + w.w * h.w;
        }
        s_hz[e][cc] = acc;
    }
    __syncthreads();

    // P2: c[e][m] = (dense_b[m] + rbf·dense_W[m,:]) * env * h_z[m%32]
    for (int idx = tid; idx < EPB * 96; idx += THREADS) {
        int e = idx / 96, m = idx - e * 96;
        int cc = m & 31;
        const float4* Wd  = (const float4*)(dense_W + m * 32);
        const float4* rb4 = (const float4*)s_rbf[e];
        float acc = dense_b[m];
        #pragma unroll
        for (int n = 0; n < 8; ++n) {
            float4 w = Wd[n]; float4 rv = rb4[n];
            acc += w.x * rv.x + w.y * rv.y + w.z * rv.z + w.w * rv.w;
        }
        s_c[e][m] = acc * s_env[e] * s_hz[e][cc];
    }
    __syncthreads();

    // P3: fully-coalesced float4 stores of all three output regions
    float* outI = out + (size_t)e0 * 288;
    float* outA = out + (size_t)N_EDGES * 288 + (size_t)e0 * 288;
    float* outS = out + (size_t)N_EDGES * 576 + (size_t)e0 * 288;
    const int NQ = EPB * 288 / 4;  // 1152 float4s per region per block
    for (int q = tid; q < NQ; q += THREADS) {
        int fbase = q * 4;
        float aI[4], aA[4], aS[4];
        #pragma unroll
        for (int u = 0; u < 4; ++u) {
            int f = fbase + u;
            int e = f / 288;
            int rem = f - e * 288;
            int cc = rem / 9;
            int p = rem - cc * 9;
            aI[u] = s_c[e][cc]      * s_basis[e][p];
            aA[u] = s_c[e][32 + cc] * s_basis[e][9 + p];
            aS[u] = s_c[e][64 + cc] * s_basis[e][18 + p];
        }
        ((float4*)outI)[q] = make_float4(aI[0], aI[1], aI[2], aI[3]);
        ((float4*)outA)[q] = make_float4(aA[0], aA[1], aA[2], aA[3]);
        ((float4*)outS)[q] = make_float4(aS[0], aS[1], aS[2], aS[3]);
    }
}

extern "C" void kernel_launch(void* const* d_in, const int* in_sizes, int n_in,
                              void* d_out, int out_size, void* d_ws, size_t ws_size,
                              hipStream_t stream) {
    const int*   an  = (const int*)d_in[0];
    const int*   nbr = (const int*)d_in[1];
    const float* ev  = (const float*)d_in[2];
    const float* zt  = (const float*)d_in[3];
    const float* zw  = (const float*)d_in[4];
    const float* dw  = (const float*)d_in[5];
    const float* db  = (const float*)d_in[6];
    const float* rb  = (const float*)d_in[7];
    const float* rc  = (const float*)d_in[8];
    float* outp = (float*)d_out;

    dim3 grid(N_EDGES / EPB);
    edge_embed_kernel<<<grid, THREADS, 0, stream>>>(
        an, nbr, ev, zt, zw, dw, db, rb, rc, outp);
}